// Round 15
// baseline (563.987 us; speedup 1.0000x reference)
//
#include <hip/hip_runtime.h>
#include <math.h>

#define NN 50000
#define EE 800000
#define CC 256
#define NS (NN * CC)
#define NBK 782        // dst buckets per relation (64 dsts each)
#define BCAP 2048      // LDS capacity per bucket in P2
#define P1T 2048       // edges per P0/P1 tile
#define NT1 391        // tiles per relation = ceil(EE / P1T)
#define TOBF_BLKS 12500
#define PREP_BLKS 2568

typedef __attribute__((ext_vector_type(4))) float f32x4;
typedef __attribute__((ext_vector_type(2))) float f32x2;
typedef __attribute__((ext_vector_type(8))) short bf16x8;
typedef __attribute__((ext_vector_type(4))) unsigned int u32x4;
typedef __attribute__((ext_vector_type(2))) unsigned int u32x2;

__device__ __forceinline__ float bf2f(unsigned int u) {
    union { unsigned int i; float f; } c; c.i = u << 16; return c.f;
}
__device__ __forceinline__ unsigned short f2bf(float f) {
    union { float f; unsigned int i; } c; c.f = f;
    unsigned int u = c.i;
    u += 0x7fffu + ((u >> 16) & 1u);
    return (unsigned short)(u >> 16);
}

// ---- fp8 e4m3 encode/decode (hw builtins on gfx950; sw fallback) ----------
#if __has_builtin(__builtin_amdgcn_cvt_f32_fp8) && __has_builtin(__builtin_amdgcn_cvt_pk_fp8_f32)
#define HW_FP8 1
#else
#define HW_FP8 0
#endif
#if __has_builtin(__builtin_amdgcn_cvt_pk_f32_fp8)
#define HW_FP8PK 1
#else
#define HW_FP8PK 0
#endif

__device__ __forceinline__ unsigned char sw_f2fp8(float f) {
    float a = fabsf(f);
    unsigned s = (f < 0.f) ? 0x80u : 0u;
    if (a >= 448.f) return (unsigned char)(s | 0x7Eu);
    if (a < 0.015625f) {
        int q = (int)(a * 512.f + 0.5f);
        return (unsigned char)(s | (unsigned)q);
    }
    int e = (int)floorf(log2f(a));
    float m = ldexpf(a, -e);
    int q = (int)(m * 8.f + 0.5f);
    if (q == 16) { q = 8; e += 1; }
    if (e > 8) return (unsigned char)(s | 0x7Eu);
    return (unsigned char)(s | ((unsigned)(e + 7) << 3) | (unsigned)(q - 8));
}
__device__ __forceinline__ float sw_fp82f(unsigned b) {
    unsigned s = (b & 0x80u) << 24;
    unsigned exp = (b >> 3) & 0xFu, man = b & 7u;
    float val = (exp == 0) ? ldexpf((float)man, -9)
                           : ldexpf((float)(8u | man), (int)exp - 10);
    unsigned r = __builtin_bit_cast(unsigned, val) | s;
    return __builtin_bit_cast(float, r);
}
__device__ __forceinline__ unsigned char f2fp8(float f) {
#if HW_FP8
    return (unsigned char)(__builtin_amdgcn_cvt_pk_fp8_f32(f, 0.f, 0, false) & 0xff);
#else
    return sw_f2fp8(f);
#endif
}
template<bool HI>
__device__ __forceinline__ f32x2 fp8pair(unsigned int w) {
#if HW_FP8PK
    return __builtin_amdgcn_cvt_pk_f32_fp8((int)w, HI);
#else
    f32x2 r;
    r[0] = sw_fp82f((w >> (HI ? 16 : 0)) & 0xffu);
    r[1] = sw_fp82f((w >> (HI ? 24 : 8)) & 0xffu);
    return r;
#endif
}

// ---------------------------------------------------------------------------
// setup: tobf (blocks [0,12500)) + prep weights ([12500,15068)) + P0 bucket
// histogram (rest). All disjoint outputs.
// WT slots: 0-1 WqT(t), 2-4 WckT(r), 5-7 WcvT(r), 8-9 WaT(t)
// ---------------------------------------------------------------------------
__global__ void setup_kernel(const float* __restrict__ hA, const float* __restrict__ hB,
                             unsigned short* __restrict__ h_bf,
                             const float* __restrict__ Wk, const float* __restrict__ bk,
                             const float* __restrict__ Wq, const float* __restrict__ bq,
                             const float* __restrict__ Wv, const float* __restrict__ bv,
                             const float* __restrict__ Wa,
                             const float* __restrict__ rel_att, const float* __restrict__ rel_msg,
                             unsigned short* __restrict__ WT, float* __restrict__ ball,
                             const int* __restrict__ d0, const int* __restrict__ d1,
                             const int* __restrict__ d2, int* __restrict__ bcnt)
{
    int b = blockIdx.x;
    const int ts[3] = {0, 1, 0};
    if (b < TOBF_BLKS) {
        int id = b * 256 + threadIdx.x;
        size_t base = (size_t)id * 8;
        const float* src = (base < (size_t)NS) ? (hA + base) : (hB + (base - NS));
        f32x4 a = *(const f32x4*)src;
        f32x4 bb2 = *(const f32x4*)(src + 4);
        u32x4 o;
        o[0] = (unsigned)f2bf(a[0]) | ((unsigned)f2bf(a[1]) << 16);
        o[1] = (unsigned)f2bf(a[2]) | ((unsigned)f2bf(a[3]) << 16);
        o[2] = (unsigned)f2bf(bb2[0]) | ((unsigned)f2bf(bb2[1]) << 16);
        o[3] = (unsigned)f2bf(bb2[2]) | ((unsigned)f2bf(bb2[3]) << 16);
        *(u32x4*)(h_bf + base) = o;
        return;
    }
    if (b >= TOBF_BLKS + PREP_BLKS) {
        int bb = b - (TOBF_BLKS + PREP_BLKS);
        int r = bb / NT1, tile = bb - r * NT1;
        const int* dp = r == 0 ? d0 : (r == 1 ? d1 : d2);
        __shared__ int hist[NBK];
        for (int i = threadIdx.x; i < NBK; i += 256) hist[i] = 0;
        __syncthreads();
        int base = tile * P1T;
        int lim = base + P1T; if (lim > EE) lim = EE;
        for (int i = base + threadIdx.x; i < lim; i += 256)
            atomicAdd(&hist[dp[i] >> 6], 1);
        __syncthreads();
        for (int i = threadIdx.x; i < NBK; i += 256)
            if (hist[i]) atomicAdd(&bcnt[r * NBK + i], hist[i]);
        return;
    }
    int id = (b - TOBF_BLKS) * 256 + threadIdx.x;
    if (id < 2 * 65536) {
        int t = id >> 16, rem = id & 65535;
        int n = rem >> 8, k = rem & 255;
        WT[t * 65536 + n * 256 + k] = f2bf(Wq[t * 65536 + k * 256 + n]);
    } else if (id < 5 * 65536) {
        int id2 = id - 2 * 65536;
        int r = id2 >> 16, rem = id2 & 65535;
        int n = rem >> 8, k = rem & 255;
        int h = n >> 5, j = n & 31;
        const float* wkb = Wk + ts[r] * 65536 + k * 256 + h * 32;
        const float* ab  = rel_att + r * 8192 + h * 1024 + j;
        float s = 0.f;
        #pragma unroll 8
        for (int d = 0; d < 32; ++d) s += wkb[d] * ab[d * 32];
        WT[(2 + r) * 65536 + n * 256 + k] = f2bf(s);
    } else if (id < 8 * 65536) {
        int id2 = id - 5 * 65536;
        int r = id2 >> 16, rem = id2 & 65535;
        int n = rem >> 8, k = rem & 255;
        int h = n >> 5, j = n & 31;
        const float* wvb = Wv + ts[r] * 65536 + k * 256 + h * 32;
        const float* mb  = rel_msg + r * 8192 + h * 1024 + j;
        float s = 0.f;
        #pragma unroll 8
        for (int d = 0; d < 32; ++d) s += wvb[d] * mb[d * 32];
        WT[(5 + r) * 65536 + n * 256 + k] = f2bf(s);
    } else if (id < 10 * 65536) {
        int id2 = id - 8 * 65536;
        int t = id2 >> 16, rem = id2 & 65535;
        int n = rem >> 8, k = rem & 255;
        WT[(8 + t) * 65536 + n * 256 + k] = f2bf(Wa[t * 65536 + k * 256 + n]);
    } else if (id < 10 * 65536 + 2048) {
        int id2 = id - 10 * 65536;
        int z = id2 >> 8, c = id2 & 255;
        float v;
        if (z < 2) {
            v = bq[z * 256 + c];
        } else if (z < 5) {
            int r = z - 2, h = c >> 5, j = c & 31;
            const float* bkb = bk + ts[r] * 256 + h * 32;
            const float* ab  = rel_att + r * 8192 + h * 1024 + j;
            v = 0.f;
            for (int d = 0; d < 32; ++d) v += bkb[d] * ab[d * 32];
        } else {
            int r = z - 5, h = c >> 5, j = c & 31;
            const float* bvb = bv + ts[r] * 256 + h * 32;
            const float* mb  = rel_msg + r * 8192 + h * 1024 + j;
            v = 0.f;
            for (int d = 0; d < 32; ++d) v += bvb[d] * mb[d * 32];
        }
        ball[z * 256 + c] = v;
    }
}

// exclusive scan of bucket counts -> bbase[r][0..NBK], init bcur
__global__ __launch_bounds__(1024) void bscan_kernel(const int* __restrict__ bcnt,
                                                     int* __restrict__ bbase,
                                                     int* __restrict__ bcur)
{
    int r = blockIdx.x;
    int t = threadIdx.x, lane = t & 63, w = t >> 6;
    __shared__ int wsum[16];
    int x = (t < NBK) ? bcnt[r * NBK + t] : 0;
    int v = x;
    #pragma unroll
    for (int ofs = 1; ofs < 64; ofs <<= 1) {
        int y = __shfl_up(v, ofs);
        if (lane >= ofs) v += y;
    }
    if (lane == 63) wsum[w] = v;
    __syncthreads();
    if (t < 16) {
        int wv = wsum[t];
        #pragma unroll
        for (int ofs = 1; ofs < 16; ofs <<= 1) {
            int y = __shfl_up(wv, ofs);
            if (t >= ofs) wv += y;
        }
        wsum[t] = wv;
    }
    __syncthreads();
    int excl = (w > 0 ? wsum[w - 1] : 0) + v - x;
    if (t < NBK) { bbase[r * (NBK + 1) + t] = excl; bcur[r * NBK + t] = excl; }
    if (t == NBK - 1) bbase[r * (NBK + 1) + NBK] = excl + x;
}

// P1: binned scatter (packed src<<6 | dst&63)
__global__ __launch_bounds__(256) void p1_kernel(const int* __restrict__ s0, const int* __restrict__ s1,
                                                 const int* __restrict__ s2,
                                                 const int* __restrict__ d0, const int* __restrict__ d1,
                                                 const int* __restrict__ d2,
                                                 int* __restrict__ bcur, unsigned int* __restrict__ srcS)
{
    int bb = blockIdx.x;
    int r = bb / NT1, tile = bb - r * NT1;
    const int* sp = r == 0 ? s0 : (r == 1 ? s1 : s2);
    const int* dp = r == 0 ? d0 : (r == 1 ? d1 : d2);
    __shared__ int hist[NBK];
    __shared__ int lbase[NBK];
    for (int i = threadIdx.x; i < NBK; i += 256) hist[i] = 0;
    __syncthreads();
    int base = tile * P1T;
    int lim = base + P1T; if (lim > EE) lim = EE;
    for (int i = base + threadIdx.x; i < lim; i += 256)
        atomicAdd(&hist[dp[i] >> 6], 1);
    __syncthreads();
    for (int i = threadIdx.x; i < NBK; i += 256)
        lbase[i] = hist[i] ? atomicAdd(&bcur[r * NBK + i], hist[i]) : 0;
    __syncthreads();
    unsigned int* out = srcS + (size_t)r * EE;
    for (int i = base + threadIdx.x; i < lim; i += 256) {
        int dv = dp[i];
        int bk = dv >> 6;
        int pos = atomicAdd(&lbase[bk], 1);
        out[pos] = ((unsigned)sp[i] << 6) | (unsigned)(dv & 63);
    }
}

// P2: per-bucket LDS counting sort by dst; emits CSR offsets
__global__ __launch_bounds__(256) void p2_kernel(const int* __restrict__ bbase,
                                                 unsigned int* __restrict__ srcS,
                                                 int* __restrict__ offs)
{
    int r = blockIdx.x / NBK, bk = blockIdx.x - r * NBK;
    int base = bbase[r * (NBK + 1) + bk];
    int n = bbase[r * (NBK + 1) + bk + 1] - base;
    unsigned int* seg = srcS + (size_t)r * EE + base;
    __shared__ unsigned int vals[BCAP];
    __shared__ unsigned int sorted[BCAP];
    __shared__ int hist[64], hcur[64];
    int t = threadIdx.x;
    if (t < 64) hist[t] = 0;
    __syncthreads();
    for (int i = t; i < n; i += 256) {
        unsigned int v = seg[i];
        vals[i] = v;
        atomicAdd(&hist[v & 63], 1);
    }
    __syncthreads();
    if (t < 64) {
        int x = hist[t], v = x;
        #pragma unroll
        for (int ofs = 1; ofs < 64; ofs <<= 1) {
            int y = __shfl_up(v, ofs);
            if (t >= ofs) v += y;
        }
        int excl = v - x;
        hcur[t] = excl;
        int d = bk * 64 + t;
        if (d < NN) offs[r * (NN + 1) + d] = base + excl;
    }
    if (bk == NBK - 1 && t == 64) offs[r * (NN + 1) + NN] = EE;
    __syncthreads();
    for (int i = t; i < n; i += 256) {
        unsigned int v = vals[i];
        int pos = atomicAdd(&hcur[v & 63], 1);
        sorted[pos] = v >> 6;
    }
    __syncthreads();
    for (int i = t; i < n; i += 256) seg[i] = sorted[i];
}

// ---------------------------------------------------------------------------
// GEMM body: A bf16, 128x128 tile, BK=64, 4 waves, XOR-swizzled LDS.
// Epilogue: bf16 (Obf, stride 256 elem) or fp8 byte (Of8, stride 512 B).
// ---------------------------------------------------------------------------
__device__ __forceinline__ void gemm_body(const unsigned short* __restrict__ A,
                                          const unsigned short* __restrict__ W,
                                          const float* __restrict__ bias,
                                          unsigned short* __restrict__ Obf,
                                          unsigned char* __restrict__ Of8,
                                          int mBase, int nBase)
{
    __shared__ __align__(16) unsigned short As[128 * 64];
    __shared__ __align__(16) unsigned short Bs[128 * 64];

    int tid = threadIdx.x;
    int lane = tid & 63, wid = tid >> 6;
    int warpM = wid >> 1, warpN = wid & 1;

    f32x4 acc[4][4];
    #pragma unroll
    for (int i = 0; i < 4; ++i)
        #pragma unroll
        for (int j = 0; j < 4; ++j) acc[i][j] = (f32x4){0.f, 0.f, 0.f, 0.f};

    for (int kt = 0; kt < 4; ++kt) {
        int k0 = kt * 64;
        __syncthreads();
        #pragma unroll
        for (int i = 0; i < 4; ++i) {
            int c = tid + i * 256;
            int row = c >> 3, cc = c & 7;
            int gr = mBase + row; if (gr > NN - 1) gr = NN - 1;
            u32x4 av = *(const u32x4*)(A + (size_t)gr * CC + k0 + cc * 8);
            int sb = row * 128 + ((cc * 16) ^ ((row & 7) << 4));
            *(u32x4*)((char*)As + sb) = av;
            u32x4 bv = *(const u32x4*)(W + (nBase + row) * 256 + k0 + cc * 8);
            *(u32x4*)((char*)Bs + sb) = bv;
        }
        __syncthreads();
        #pragma unroll
        for (int kk = 0; kk < 2; ++kk) {
            bf16x8 af[4], bfr[4];
            int kb = kk * 64 + (lane >> 4) * 16;
            #pragma unroll
            for (int mi = 0; mi < 4; ++mi) {
                int row = warpM * 64 + mi * 16 + (lane & 15);
                int sb = row * 128 + (kb ^ ((row & 7) << 4));
                af[mi] = *(const bf16x8*)((const char*)As + sb);
            }
            #pragma unroll
            for (int ni = 0; ni < 4; ++ni) {
                int row = warpN * 64 + ni * 16 + (lane & 15);
                int sb = row * 128 + (kb ^ ((row & 7) << 4));
                bfr[ni] = *(const bf16x8*)((const char*)Bs + sb);
            }
            #pragma unroll
            for (int mi = 0; mi < 4; ++mi)
                #pragma unroll
                for (int ni = 0; ni < 4; ++ni)
                    acc[mi][ni] = __builtin_amdgcn_mfma_f32_16x16x32_bf16(af[mi], bfr[ni], acc[mi][ni], 0, 0, 0);
        }
    }

    #pragma unroll
    for (int mi = 0; mi < 4; ++mi) {
        #pragma unroll
        for (int ni = 0; ni < 4; ++ni) {
            int col = nBase + warpN * 64 + ni * 16 + (lane & 15);
            int row0 = mBase + warpM * 64 + mi * 16 + (lane >> 4) * 4;
            float b = bias[col];
            #pragma unroll
            for (int j = 0; j < 4; ++j) {
                int row = row0 + j;
                if (row < NN) {
                    float val = acc[mi][ni][j] + b;
                    if (Of8) Of8[(size_t)row * 512 + col] = f2fp8(val);
                    else     Obf[(size_t)row * 256 + col] = f2bf(val);
                }
            }
        }
    }
}

// 8 production GEMM slots, 1D grid with (slot,ntile) FASTEST-varying:
// bid = mtile*16 + slot*2 + ntile -> 16 blocks sharing an A-tile run
// concurrently -> A served from L3 once.
__global__ __launch_bounds__(256, 2)
void gemm8_kernel(const unsigned short* __restrict__ h_bf,
                  const unsigned short* __restrict__ WT, const float* __restrict__ ball,
                  unsigned short* __restrict__ Qb, unsigned char* __restrict__ KV0,
                  unsigned char* __restrict__ KV1, unsigned char* __restrict__ KV2)
{
    int bid = blockIdx.x;
    int mtile = bid >> 4;
    int rem = bid & 15;
    int z = rem >> 1;
    int ntile = rem & 1;
    const unsigned short* A = (z == 1 || z == 3 || z == 6) ? (h_bf + (size_t)NS) : h_bf;
    unsigned short* Obf = nullptr;
    unsigned char* Of8 = nullptr;
    switch (z) {
        case 0: Obf = Qb;               break;
        case 1: Obf = Qb + (size_t)NS;  break;
        case 2: Of8 = KV0;              break;
        case 3: Of8 = KV1;              break;
        case 4: Of8 = KV2;              break;
        case 5: Of8 = KV0 + 256;        break;
        case 6: Of8 = KV1 + 256;        break;
        default: Of8 = KV2 + 256;       break;
    }
    gemm_body(A, WT + z * 65536, ball + z * 256, Obf, Of8,
              mtile * 128, ntile * 128);
}

// ---------------------------------------------------------------------------
// Output GEMM: A bf16 (z=1: average of two bf16 buffers t0,t2 during staging),
// out f32 with skip-residual.
// ---------------------------------------------------------------------------
__global__ __launch_bounds__(256, 2)
void out_gemm_kernel(const unsigned short* __restrict__ A0, const unsigned short* __restrict__ A1,
                     const unsigned short* __restrict__ A1b,
                     const unsigned short* __restrict__ W0, const unsigned short* __restrict__ W1,
                     const float* __restrict__ b0, const float* __restrict__ b1,
                     float* __restrict__ OutF,
                     const float* __restrict__ hA, const float* __restrict__ hB,
                     const float* __restrict__ skip)
{
    int z = blockIdx.z;
    const unsigned short* A = z ? A1 : A0;
    const unsigned short* W = z ? W1 : W0;
    const float* bias = z ? b1 : b0;
    int mBase = blockIdx.x * 128;
    int nBase = blockIdx.y * 128;

    __shared__ __align__(16) unsigned short As[128 * 64];
    __shared__ __align__(16) unsigned short Bs[128 * 64];

    int tid = threadIdx.x;
    int lane = tid & 63, wid = tid >> 6;
    int warpM = wid >> 1, warpN = wid & 1;

    f32x4 acc[4][4];
    #pragma unroll
    for (int i = 0; i < 4; ++i)
        #pragma unroll
        for (int j = 0; j < 4; ++j) acc[i][j] = (f32x4){0.f, 0.f, 0.f, 0.f};

    for (int kt = 0; kt < 4; ++kt) {
        int k0 = kt * 64;
        __syncthreads();
        #pragma unroll
        for (int i = 0; i < 4; ++i) {
            int c = tid + i * 256;
            int row = c >> 3, cc = c & 7;
            int gr = mBase + row; if (gr > NN - 1) gr = NN - 1;
            size_t aofs = (size_t)gr * CC + k0 + cc * 8;
            u32x4 av = *(const u32x4*)(A + aofs);
            if (z) {
                u32x4 av2 = *(const u32x4*)(A1b + aofs);
                #pragma unroll
                for (int q = 0; q < 4; ++q) {
                    float lo = (bf2f(av[q] & 0xffffu) + bf2f(av2[q] & 0xffffu)) * 0.5f;
                    float hi = (bf2f(av[q] >> 16) + bf2f(av2[q] >> 16)) * 0.5f;
                    av[q] = (unsigned)f2bf(lo) | ((unsigned)f2bf(hi) << 16);
                }
            }
            int sb = row * 128 + ((cc * 16) ^ ((row & 7) << 4));
            *(u32x4*)((char*)As + sb) = av;
            u32x4 bv = *(const u32x4*)(W + (nBase + row) * 256 + k0 + cc * 8);
            *(u32x4*)((char*)Bs + sb) = bv;
        }
        __syncthreads();
        #pragma unroll
        for (int kk = 0; kk < 2; ++kk) {
            bf16x8 af[4], bfr[4];
            int kb = kk * 64 + (lane >> 4) * 16;
            #pragma unroll
            for (int mi = 0; mi < 4; ++mi) {
                int row = warpM * 64 + mi * 16 + (lane & 15);
                int sb = row * 128 + (kb ^ ((row & 7) << 4));
                af[mi] = *(const bf16x8*)((const char*)As + sb);
            }
            #pragma unroll
            for (int ni = 0; ni < 4; ++ni) {
                int row = warpN * 64 + ni * 16 + (lane & 15);
                int sb = row * 128 + (kb ^ ((row & 7) << 4));
                bfr[ni] = *(const bf16x8*)((const char*)Bs + sb);
            }
            #pragma unroll
            for (int mi = 0; mi < 4; ++mi)
                #pragma unroll
                for (int ni = 0; ni < 4; ++ni)
                    acc[mi][ni] = __builtin_amdgcn_mfma_f32_16x16x32_bf16(af[mi], bfr[ni], acc[mi][ni], 0, 0, 0);
        }
    }

    float alpha = 1.f / (1.f + __expf(-skip[z]));
    const float* hres = z ? hB : hA;

    #pragma unroll
    for (int mi = 0; mi < 4; ++mi) {
        #pragma unroll
        for (int ni = 0; ni < 4; ++ni) {
            int col = nBase + warpN * 64 + ni * 16 + (lane & 15);
            int row0 = mBase + warpM * 64 + mi * 16 + (lane >> 4) * 4;
            float b = bias[col];
            #pragma unroll
            for (int j = 0; j < 4; ++j) {
                int row = row0 + j;
                if (row < NN) {
                    float val = acc[mi][ni][j] + b;
                    float hv = hres[(size_t)row * CC + col];
                    OutF[(size_t)z * NS + (size_t)row * CC + col] = val * alpha + hv * (1.f - alpha);
                }
            }
        }
    }
}

// ---------------------------------------------------------------------------
// Edge aggregation, ALL relations in one launch, ONE pass per wave:
// w<NN: r0->TbB; [NN,2NN): r1->TbA; [2NN,3NN): r2->T2b.
// fp8 K/V (512B/src row), packed pk decode, exp2 softmax, 1-edge prefetch.
// ---------------------------------------------------------------------------
__device__ __forceinline__ void agg_pass(const unsigned char* __restrict__ KV,
                                         const int* __restrict__ srcS,
                                         int beg, int end, int lane,
                                         float q0, float q1, float q2, float q3, float ps2,
                                         float& o0, float& o1, float& o2, float& o3)
{
    float l = 0.f;
    float a0 = 0.f, a1 = 0.f, a2 = 0.f, a3 = 0.f;
    int n = end - beg;
    if (n > 0) {
        int p0 = beg + lane;
        int idx = srcS[p0 < end ? p0 : end - 1];
        int s = __shfl(idx, 0);
        unsigned int kw = *(const unsigned int*)(KV + (size_t)s * 512 + lane * 4);
        unsigned int vw = *(const unsigned int*)(KV + (size_t)s * 512 + 256 + lane * 4);
        for (int j = 0; j < n; ++j) {
            unsigned int kc = kw, vc = vw;
            int jn = j + 1;
            if (jn < n) {
                if ((jn & 63) == 0) {
                    int p = beg + jn + lane;
                    idx = srcS[p < end ? p : end - 1];
                }
                int sn = __shfl(idx, jn & 63);
                kw = *(const unsigned int*)(KV + (size_t)sn * 512 + lane * 4);
                vw = *(const unsigned int*)(KV + (size_t)sn * 512 + 256 + lane * 4);
            }
            f32x2 k01 = fp8pair<false>(kc), k23 = fp8pair<true>(kc);
            float d = fmaf(q0, k01[0], fmaf(q1, k01[1], fmaf(q2, k23[0], q3 * k23[1])));
            d += __shfl_xor(d, 1);
            d += __shfl_xor(d, 2);
            d += __shfl_xor(d, 4);
            float pw = exp2f(d * ps2);
            l += pw;
            f32x2 v01 = fp8pair<false>(vc), v23 = fp8pair<true>(vc);
            a0 = fmaf(pw, v01[0], a0);
            a1 = fmaf(pw, v01[1], a1);
            a2 = fmaf(pw, v23[0], a2);
            a3 = fmaf(pw, v23[1], a3);
        }
    }
    float inv = (l > 0.f) ? 1.f / l : 0.f;
    o0 = a0 * inv; o1 = a1 * inv; o2 = a2 * inv; o3 = a3 * inv;
}

__global__ __launch_bounds__(256)
void agg_all_kernel(const unsigned short* __restrict__ Q0, const unsigned short* __restrict__ Q1,
                    const unsigned char* __restrict__ KV0, const unsigned char* __restrict__ KV1,
                    const unsigned char* __restrict__ KV2,
                    const int* __restrict__ offs, const int* __restrict__ srcS,
                    const float* __restrict__ rel_pri,
                    unsigned short* __restrict__ TbA, unsigned short* __restrict__ TbB,
                    unsigned short* __restrict__ T2b)
{
    int w = (blockIdx.x * 256 + threadIdx.x) >> 6;
    if (w >= 3 * NN) return;
    int lane = threadIdx.x & 63;
    int h = lane >> 3;
    const float rs2 = 0.17677669529663687f * 1.4426950408889634f;  // /sqrt(32)*log2(e)

    int r = (w < NN) ? 0 : (w < 2 * NN ? 1 : 2);
    int d = w - r * NN;
    const unsigned short* Q = (r == 1) ? Q0 : Q1;
    const unsigned char* KV = (r == 0) ? KV0 : (r == 1 ? KV1 : KV2);
    unsigned short* T = (r == 0) ? TbB : (r == 1 ? TbA : T2b);

    u32x2 qv = *(const u32x2*)(Q + (size_t)d * CC + lane * 4);
    float q0 = bf2f(qv[0] & 0xffffu), q1 = bf2f(qv[0] >> 16);
    float q2 = bf2f(qv[1] & 0xffffu), q3 = bf2f(qv[1] >> 16);
    const int* off = offs + r * (NN + 1);
    float x0, x1, x2, x3;
    agg_pass(KV, (const int*)srcS + (size_t)r * EE, off[d], off[d + 1], lane,
             q0, q1, q2, q3, rel_pri[r * 8 + h] * rs2, x0, x1, x2, x3);
    unsigned short* out = T + (size_t)d * CC + lane * 4;
    u32x2 o;
    o[0] = (unsigned)f2bf(x0) | ((unsigned)f2bf(x1) << 16);
    o[1] = (unsigned)f2bf(x2) | ((unsigned)f2bf(x3) << 16);
    *(u32x2*)out = o;
}

// ---------------------------------------------------------------------------
extern "C" void kernel_launch(void* const* d_in, const int* in_sizes, int n_in,
                              void* d_out, int out_size, void* d_ws, size_t ws_size,
                              hipStream_t stream)
{
    const float* hA = (const float*)d_in[0];
    const float* hB = (const float*)d_in[1];
    const int* src0 = (const int*)d_in[2];
    const int* dst0 = (const int*)d_in[3];
    const int* src1 = (const int*)d_in[4];
    const int* dst1 = (const int*)d_in[5];
    const int* src2 = (const int*)d_in[6];
    const int* dst2 = (const int*)d_in[7];
    const float* Wk = (const float*)d_in[8];
    const float* bk = (const float*)d_in[9];
    const float* Wq = (const float*)d_in[10];
    const float* bq = (const float*)d_in[11];
    const float* Wv = (const float*)d_in[12];
    const float* bv = (const float*)d_in[13];
    const float* Wa = (const float*)d_in[14];
    const float* ba = (const float*)d_in[15];
    const float* rel_att = (const float*)d_in[16];
    const float* rel_msg = (const float*)d_in[17];
    const float* rel_pri = (const float*)d_in[18];
    const float* skip = (const float*)d_in[19];

    char* w = (char*)d_ws;
    auto alloc = [&](size_t bytes) {
        char* p = w;
        w += (bytes + 255) & ~(size_t)255;
        return p;
    };
    // ws total ~166 MB (proven budget)
    unsigned short* WT  = (unsigned short*)alloc((size_t)10 * 65536 * 2);
    float* ball         = (float*)alloc((size_t)8 * 256 * 4);
    unsigned short* Qb  = (unsigned short*)alloc((size_t)2 * NS * 2);   // Q0,Q1 (bf16)
    unsigned char* KV0  = (unsigned char*)alloc((size_t)NN * 512);      // r0 K|V fp8
    unsigned short* Tb  = (unsigned short*)alloc((size_t)2 * NS * 2);   // t0->TbB, t1->TbA
    unsigned short* T2b = (unsigned short*)alloc((size_t)NS * 2);       // t2 (bf16)
    int* offs           = (int*)alloc((size_t)3 * (NN + 1) * 4);
    int* srcS           = (int*)alloc((size_t)3 * EE * 4);
    int* bcnt           = (int*)alloc((size_t)3 * NBK * 4);
    int* bbase          = (int*)alloc((size_t)3 * (NBK + 1) * 4);
    int* bcur           = (int*)alloc((size_t)3 * NBK * 4);

    // d_out (102.4 MB, dead until out_gemm): KV1 | KV2 | h_bf (bf16 hA,hB)
    unsigned char* dob = (unsigned char*)d_out;
    unsigned char* KV1 = dob;
    unsigned char* KV2 = dob + (size_t)NN * 512;
    unsigned short* h_bf = (unsigned short*)(dob + (size_t)2 * NN * 512);

    (void)hipMemsetAsync(bcnt, 0, (size_t)3 * NBK * 4, stream);

    // tobf + prep weights + P0 bucket histogram (fused, disjoint block ranges)
    setup_kernel<<<TOBF_BLKS + PREP_BLKS + 3 * NT1, 256, 0, stream>>>(
        hA, hB, h_bf, Wk, bk, Wq, bq, Wv, bv, Wa,
        rel_att, rel_msg, WT, ball, dst0, dst1, dst2, bcnt);
    bscan_kernel<<<3, 1024, 0, stream>>>(bcnt, bbase, bcur);
    p1_kernel<<<3 * NT1, 256, 0, stream>>>(src0, src1, src2, dst0, dst1, dst2,
                                           bcur, (unsigned int*)srcS);
    p2_kernel<<<3 * NBK, 256, 0, stream>>>(bbase, (unsigned int*)srcS, offs);

    // all 8 production GEMMs; (slot,ntile) fastest -> A-tile L3 reuse
    gemm8_kernel<<<391 * 16, 256, 0, stream>>>(h_bf, WT, ball, Qb, KV0, KV1, KV2);

    // all 3 relations, one pass per wave (r2 -> T2b, averaged in out_gemm)
    agg_all_kernel<<<37500, 256, 0, stream>>>(Qb, Qb + NS, KV0, KV1, KV2,
                                              offs, srcS, rel_pri,
                                              Tb, Tb + NS, T2b);

    // output GEMM overwrites d_out; z=1 A-operand = (TbB + T2b)/2 on the fly
    out_gemm_kernel<<<dim3(391, 2, 2), 256, 0, stream>>>(
        Tb, Tb + NS, T2b, WT + 8 * 65536, WT + 9 * 65536, ba, ba + 256,
        (float*)d_out, hA, hB, skip);
}

// Round 16
// 524.858 us; speedup vs baseline: 1.0746x; 1.0746x over previous
//
#include <hip/hip_runtime.h>
#include <math.h>

#define NN 50000
#define EE 800000
#define CC 256
#define NS (NN * CC)
#define NBK 782        // dst buckets per relation (64 dsts each)
#define BCAP 2048      // LDS capacity per bucket in P2
#define P1T 2048       // edges per P0/P1 tile
#define NT1 391        // tiles per relation = ceil(EE / P1T)
#define TOBF_BLKS 12500
#define PREP_BLKS 2568

typedef __attribute__((ext_vector_type(4))) float f32x4;
typedef __attribute__((ext_vector_type(2))) float f32x2;
typedef __attribute__((ext_vector_type(8))) short bf16x8;
typedef __attribute__((ext_vector_type(4))) unsigned int u32x4;
typedef __attribute__((ext_vector_type(2))) unsigned int u32x2;

__device__ __forceinline__ float bf2f(unsigned int u) {
    union { unsigned int i; float f; } c; c.i = u << 16; return c.f;
}
__device__ __forceinline__ unsigned short f2bf(float f) {
    union { float f; unsigned int i; } c; c.f = f;
    unsigned int u = c.i;
    u += 0x7fffu + ((u >> 16) & 1u);
    return (unsigned short)(u >> 16);
}

// ---- fp8 e4m3 encode/decode (hw builtins on gfx950; sw fallback) ----------
#if __has_builtin(__builtin_amdgcn_cvt_f32_fp8) && __has_builtin(__builtin_amdgcn_cvt_pk_fp8_f32)
#define HW_FP8 1
#else
#define HW_FP8 0
#endif
#if __has_builtin(__builtin_amdgcn_cvt_pk_f32_fp8)
#define HW_FP8PK 1
#else
#define HW_FP8PK 0
#endif

__device__ __forceinline__ unsigned char sw_f2fp8(float f) {
    float a = fabsf(f);
    unsigned s = (f < 0.f) ? 0x80u : 0u;
    if (a >= 448.f) return (unsigned char)(s | 0x7Eu);
    if (a < 0.015625f) {
        int q = (int)(a * 512.f + 0.5f);
        return (unsigned char)(s | (unsigned)q);
    }
    int e = (int)floorf(log2f(a));
    float m = ldexpf(a, -e);
    int q = (int)(m * 8.f + 0.5f);
    if (q == 16) { q = 8; e += 1; }
    if (e > 8) return (unsigned char)(s | 0x7Eu);
    return (unsigned char)(s | ((unsigned)(e + 7) << 3) | (unsigned)(q - 8));
}
__device__ __forceinline__ float sw_fp82f(unsigned b) {
    unsigned s = (b & 0x80u) << 24;
    unsigned exp = (b >> 3) & 0xFu, man = b & 7u;
    float val = (exp == 0) ? ldexpf((float)man, -9)
                           : ldexpf((float)(8u | man), (int)exp - 10);
    unsigned r = __builtin_bit_cast(unsigned, val) | s;
    return __builtin_bit_cast(float, r);
}
__device__ __forceinline__ unsigned char f2fp8(float f) {
#if HW_FP8
    return (unsigned char)(__builtin_amdgcn_cvt_pk_fp8_f32(f, 0.f, 0, false) & 0xff);
#else
    return sw_f2fp8(f);
#endif
}
template<bool HI>
__device__ __forceinline__ f32x2 fp8pair(unsigned int w) {
#if HW_FP8PK
    return __builtin_amdgcn_cvt_pk_f32_fp8((int)w, HI);
#else
    f32x2 r;
    r[0] = sw_fp82f((w >> (HI ? 16 : 0)) & 0xffu);
    r[1] = sw_fp82f((w >> (HI ? 24 : 8)) & 0xffu);
    return r;
#endif
}

// ---------------------------------------------------------------------------
// setup: tobf (blocks [0,12500)) + prep weights ([12500,15068)) + P0 bucket
// histogram (rest). All disjoint outputs.
// WT slots: 0-1 WqT(t), 2-4 WckT(r), 5-7 WcvT(r), 8-9 WaT(t)
// ---------------------------------------------------------------------------
__global__ void setup_kernel(const float* __restrict__ hA, const float* __restrict__ hB,
                             unsigned short* __restrict__ h_bf,
                             const float* __restrict__ Wk, const float* __restrict__ bk,
                             const float* __restrict__ Wq, const float* __restrict__ bq,
                             const float* __restrict__ Wv, const float* __restrict__ bv,
                             const float* __restrict__ Wa,
                             const float* __restrict__ rel_att, const float* __restrict__ rel_msg,
                             unsigned short* __restrict__ WT, float* __restrict__ ball,
                             const int* __restrict__ d0, const int* __restrict__ d1,
                             const int* __restrict__ d2, int* __restrict__ bcnt)
{
    int b = blockIdx.x;
    const int ts[3] = {0, 1, 0};
    if (b < TOBF_BLKS) {
        int id = b * 256 + threadIdx.x;
        size_t base = (size_t)id * 8;
        const float* src = (base < (size_t)NS) ? (hA + base) : (hB + (base - NS));
        f32x4 a = *(const f32x4*)src;
        f32x4 bb2 = *(const f32x4*)(src + 4);
        u32x4 o;
        o[0] = (unsigned)f2bf(a[0]) | ((unsigned)f2bf(a[1]) << 16);
        o[1] = (unsigned)f2bf(a[2]) | ((unsigned)f2bf(a[3]) << 16);
        o[2] = (unsigned)f2bf(bb2[0]) | ((unsigned)f2bf(bb2[1]) << 16);
        o[3] = (unsigned)f2bf(bb2[2]) | ((unsigned)f2bf(bb2[3]) << 16);
        *(u32x4*)(h_bf + base) = o;
        return;
    }
    if (b >= TOBF_BLKS + PREP_BLKS) {
        int bb = b - (TOBF_BLKS + PREP_BLKS);
        int r = bb / NT1, tile = bb - r * NT1;
        const int* dp = r == 0 ? d0 : (r == 1 ? d1 : d2);
        __shared__ int hist[NBK];
        for (int i = threadIdx.x; i < NBK; i += 256) hist[i] = 0;
        __syncthreads();
        int base = tile * P1T;
        int lim = base + P1T; if (lim > EE) lim = EE;
        for (int i = base + threadIdx.x; i < lim; i += 256)
            atomicAdd(&hist[dp[i] >> 6], 1);
        __syncthreads();
        for (int i = threadIdx.x; i < NBK; i += 256)
            if (hist[i]) atomicAdd(&bcnt[r * NBK + i], hist[i]);
        return;
    }
    int id = (b - TOBF_BLKS) * 256 + threadIdx.x;
    if (id < 2 * 65536) {
        int t = id >> 16, rem = id & 65535;
        int n = rem >> 8, k = rem & 255;
        WT[t * 65536 + n * 256 + k] = f2bf(Wq[t * 65536 + k * 256 + n]);
    } else if (id < 5 * 65536) {
        int id2 = id - 2 * 65536;
        int r = id2 >> 16, rem = id2 & 65535;
        int n = rem >> 8, k = rem & 255;
        int h = n >> 5, j = n & 31;
        const float* wkb = Wk + ts[r] * 65536 + k * 256 + h * 32;
        const float* ab  = rel_att + r * 8192 + h * 1024 + j;
        float s = 0.f;
        #pragma unroll 8
        for (int d = 0; d < 32; ++d) s += wkb[d] * ab[d * 32];
        WT[(2 + r) * 65536 + n * 256 + k] = f2bf(s);
    } else if (id < 8 * 65536) {
        int id2 = id - 5 * 65536;
        int r = id2 >> 16, rem = id2 & 65535;
        int n = rem >> 8, k = rem & 255;
        int h = n >> 5, j = n & 31;
        const float* wvb = Wv + ts[r] * 65536 + k * 256 + h * 32;
        const float* mb  = rel_msg + r * 8192 + h * 1024 + j;
        float s = 0.f;
        #pragma unroll 8
        for (int d = 0; d < 32; ++d) s += wvb[d] * mb[d * 32];
        WT[(5 + r) * 65536 + n * 256 + k] = f2bf(s);
    } else if (id < 10 * 65536) {
        int id2 = id - 8 * 65536;
        int t = id2 >> 16, rem = id2 & 65535;
        int n = rem >> 8, k = rem & 255;
        WT[(8 + t) * 65536 + n * 256 + k] = f2bf(Wa[t * 65536 + k * 256 + n]);
    } else if (id < 10 * 65536 + 2048) {
        int id2 = id - 10 * 65536;
        int z = id2 >> 8, c = id2 & 255;
        float v;
        if (z < 2) {
            v = bq[z * 256 + c];
        } else if (z < 5) {
            int r = z - 2, h = c >> 5, j = c & 31;
            const float* bkb = bk + ts[r] * 256 + h * 32;
            const float* ab  = rel_att + r * 8192 + h * 1024 + j;
            v = 0.f;
            for (int d = 0; d < 32; ++d) v += bkb[d] * ab[d * 32];
        } else {
            int r = z - 5, h = c >> 5, j = c & 31;
            const float* bvb = bv + ts[r] * 256 + h * 32;
            const float* mb  = rel_msg + r * 8192 + h * 1024 + j;
            v = 0.f;
            for (int d = 0; d < 32; ++d) v += bvb[d] * mb[d * 32];
        }
        ball[z * 256 + c] = v;
    }
}

// exclusive scan of bucket counts -> bbase[r][0..NBK], init bcur
__global__ __launch_bounds__(1024) void bscan_kernel(const int* __restrict__ bcnt,
                                                     int* __restrict__ bbase,
                                                     int* __restrict__ bcur)
{
    int r = blockIdx.x;
    int t = threadIdx.x, lane = t & 63, w = t >> 6;
    __shared__ int wsum[16];
    int x = (t < NBK) ? bcnt[r * NBK + t] : 0;
    int v = x;
    #pragma unroll
    for (int ofs = 1; ofs < 64; ofs <<= 1) {
        int y = __shfl_up(v, ofs);
        if (lane >= ofs) v += y;
    }
    if (lane == 63) wsum[w] = v;
    __syncthreads();
    if (t < 16) {
        int wv = wsum[t];
        #pragma unroll
        for (int ofs = 1; ofs < 16; ofs <<= 1) {
            int y = __shfl_up(wv, ofs);
            if (t >= ofs) wv += y;
        }
        wsum[t] = wv;
    }
    __syncthreads();
    int excl = (w > 0 ? wsum[w - 1] : 0) + v - x;
    if (t < NBK) { bbase[r * (NBK + 1) + t] = excl; bcur[r * NBK + t] = excl; }
    if (t == NBK - 1) bbase[r * (NBK + 1) + NBK] = excl + x;
}

// P1: binned scatter (packed src<<6 | dst&63)
__global__ __launch_bounds__(256) void p1_kernel(const int* __restrict__ s0, const int* __restrict__ s1,
                                                 const int* __restrict__ s2,
                                                 const int* __restrict__ d0, const int* __restrict__ d1,
                                                 const int* __restrict__ d2,
                                                 int* __restrict__ bcur, unsigned int* __restrict__ srcS)
{
    int bb = blockIdx.x;
    int r = bb / NT1, tile = bb - r * NT1;
    const int* sp = r == 0 ? s0 : (r == 1 ? s1 : s2);
    const int* dp = r == 0 ? d0 : (r == 1 ? d1 : d2);
    __shared__ int hist[NBK];
    __shared__ int lbase[NBK];
    for (int i = threadIdx.x; i < NBK; i += 256) hist[i] = 0;
    __syncthreads();
    int base = tile * P1T;
    int lim = base + P1T; if (lim > EE) lim = EE;
    for (int i = base + threadIdx.x; i < lim; i += 256)
        atomicAdd(&hist[dp[i] >> 6], 1);
    __syncthreads();
    for (int i = threadIdx.x; i < NBK; i += 256)
        lbase[i] = hist[i] ? atomicAdd(&bcur[r * NBK + i], hist[i]) : 0;
    __syncthreads();
    unsigned int* out = srcS + (size_t)r * EE;
    for (int i = base + threadIdx.x; i < lim; i += 256) {
        int dv = dp[i];
        int bk = dv >> 6;
        int pos = atomicAdd(&lbase[bk], 1);
        out[pos] = ((unsigned)sp[i] << 6) | (unsigned)(dv & 63);
    }
}

// P2: per-bucket LDS counting sort by dst; emits CSR offsets
__global__ __launch_bounds__(256) void p2_kernel(const int* __restrict__ bbase,
                                                 unsigned int* __restrict__ srcS,
                                                 int* __restrict__ offs)
{
    int r = blockIdx.x / NBK, bk = blockIdx.x - r * NBK;
    int base = bbase[r * (NBK + 1) + bk];
    int n = bbase[r * (NBK + 1) + bk + 1] - base;
    unsigned int* seg = srcS + (size_t)r * EE + base;
    __shared__ unsigned int vals[BCAP];
    __shared__ unsigned int sorted[BCAP];
    __shared__ int hist[64], hcur[64];
    int t = threadIdx.x;
    if (t < 64) hist[t] = 0;
    __syncthreads();
    for (int i = t; i < n; i += 256) {
        unsigned int v = seg[i];
        vals[i] = v;
        atomicAdd(&hist[v & 63], 1);
    }
    __syncthreads();
    if (t < 64) {
        int x = hist[t], v = x;
        #pragma unroll
        for (int ofs = 1; ofs < 64; ofs <<= 1) {
            int y = __shfl_up(v, ofs);
            if (t >= ofs) v += y;
        }
        int excl = v - x;
        hcur[t] = excl;
        int d = bk * 64 + t;
        if (d < NN) offs[r * (NN + 1) + d] = base + excl;
    }
    if (bk == NBK - 1 && t == 64) offs[r * (NN + 1) + NN] = EE;
    __syncthreads();
    for (int i = t; i < n; i += 256) {
        unsigned int v = vals[i];
        int pos = atomicAdd(&hcur[v & 63], 1);
        sorted[pos] = v >> 6;
    }
    __syncthreads();
    for (int i = t; i < n; i += 256) seg[i] = sorted[i];
}

// ---------------------------------------------------------------------------
// GEMM body: A bf16, 128x128 tile, BK=64, 4 waves, XOR-swizzled LDS.
// Epilogue: bf16 (Obf, stride 256 elem) or fp8 byte (Of8, stride 512 B).
// ---------------------------------------------------------------------------
__device__ __forceinline__ void gemm_body(const unsigned short* __restrict__ A,
                                          const unsigned short* __restrict__ W,
                                          const float* __restrict__ bias,
                                          unsigned short* __restrict__ Obf,
                                          unsigned char* __restrict__ Of8,
                                          int mBase, int nBase)
{
    __shared__ __align__(16) unsigned short As[128 * 64];
    __shared__ __align__(16) unsigned short Bs[128 * 64];

    int tid = threadIdx.x;
    int lane = tid & 63, wid = tid >> 6;
    int warpM = wid >> 1, warpN = wid & 1;

    f32x4 acc[4][4];
    #pragma unroll
    for (int i = 0; i < 4; ++i)
        #pragma unroll
        for (int j = 0; j < 4; ++j) acc[i][j] = (f32x4){0.f, 0.f, 0.f, 0.f};

    for (int kt = 0; kt < 4; ++kt) {
        int k0 = kt * 64;
        __syncthreads();
        #pragma unroll
        for (int i = 0; i < 4; ++i) {
            int c = tid + i * 256;
            int row = c >> 3, cc = c & 7;
            int gr = mBase + row; if (gr > NN - 1) gr = NN - 1;
            u32x4 av = *(const u32x4*)(A + (size_t)gr * CC + k0 + cc * 8);
            int sb = row * 128 + ((cc * 16) ^ ((row & 7) << 4));
            *(u32x4*)((char*)As + sb) = av;
            u32x4 bv = *(const u32x4*)(W + (nBase + row) * 256 + k0 + cc * 8);
            *(u32x4*)((char*)Bs + sb) = bv;
        }
        __syncthreads();
        #pragma unroll
        for (int kk = 0; kk < 2; ++kk) {
            bf16x8 af[4], bfr[4];
            int kb = kk * 64 + (lane >> 4) * 16;
            #pragma unroll
            for (int mi = 0; mi < 4; ++mi) {
                int row = warpM * 64 + mi * 16 + (lane & 15);
                int sb = row * 128 + (kb ^ ((row & 7) << 4));
                af[mi] = *(const bf16x8*)((const char*)As + sb);
            }
            #pragma unroll
            for (int ni = 0; ni < 4; ++ni) {
                int row = warpN * 64 + ni * 16 + (lane & 15);
                int sb = row * 128 + (kb ^ ((row & 7) << 4));
                bfr[ni] = *(const bf16x8*)((const char*)Bs + sb);
            }
            #pragma unroll
            for (int mi = 0; mi < 4; ++mi)
                #pragma unroll
                for (int ni = 0; ni < 4; ++ni)
                    acc[mi][ni] = __builtin_amdgcn_mfma_f32_16x16x32_bf16(af[mi], bfr[ni], acc[mi][ni], 0, 0, 0);
        }
    }

    #pragma unroll
    for (int mi = 0; mi < 4; ++mi) {
        #pragma unroll
        for (int ni = 0; ni < 4; ++ni) {
            int col = nBase + warpN * 64 + ni * 16 + (lane & 15);
            int row0 = mBase + warpM * 64 + mi * 16 + (lane >> 4) * 4;
            float b = bias[col];
            #pragma unroll
            for (int j = 0; j < 4; ++j) {
                int row = row0 + j;
                if (row < NN) {
                    float val = acc[mi][ni][j] + b;
                    if (Of8) Of8[(size_t)row * 512 + col] = f2fp8(val);
                    else     Obf[(size_t)row * 256 + col] = f2bf(val);
                }
            }
        }
    }
}

// 8 production GEMM slots, 1D grid with (slot,ntile) FASTEST-varying:
// bid = mtile*16 + slot*2 + ntile -> 16 blocks sharing an A-tile run
// concurrently -> A served from L3 once.
__global__ __launch_bounds__(256, 2)
void gemm8_kernel(const unsigned short* __restrict__ h_bf,
                  const unsigned short* __restrict__ WT, const float* __restrict__ ball,
                  unsigned short* __restrict__ Qb, unsigned char* __restrict__ KV0,
                  unsigned char* __restrict__ KV1, unsigned char* __restrict__ KV2)
{
    int bid = blockIdx.x;
    int mtile = bid >> 4;
    int rem = bid & 15;
    int z = rem >> 1;
    int ntile = rem & 1;
    const unsigned short* A = (z == 1 || z == 3 || z == 6) ? (h_bf + (size_t)NS) : h_bf;
    unsigned short* Obf = nullptr;
    unsigned char* Of8 = nullptr;
    switch (z) {
        case 0: Obf = Qb;               break;
        case 1: Obf = Qb + (size_t)NS;  break;
        case 2: Of8 = KV0;              break;
        case 3: Of8 = KV1;              break;
        case 4: Of8 = KV2;              break;
        case 5: Of8 = KV0 + 256;        break;
        case 6: Of8 = KV1 + 256;        break;
        default: Of8 = KV2 + 256;       break;
    }
    gemm_body(A, WT + z * 65536, ball + z * 256, Obf, Of8,
              mtile * 128, ntile * 128);
}

// ---------------------------------------------------------------------------
// Output GEMM: A bf16, out f32 with skip-residual (residual from f32 inputs).
// ---------------------------------------------------------------------------
__global__ __launch_bounds__(256, 2)
void out_gemm_kernel(const unsigned short* __restrict__ A0, const unsigned short* __restrict__ A1,
                     const unsigned short* __restrict__ W0, const unsigned short* __restrict__ W1,
                     const float* __restrict__ b0, const float* __restrict__ b1,
                     float* __restrict__ OutF,
                     const float* __restrict__ hA, const float* __restrict__ hB,
                     const float* __restrict__ skip)
{
    int z = blockIdx.z;
    const unsigned short* A = z ? A1 : A0;
    const unsigned short* W = z ? W1 : W0;
    const float* bias = z ? b1 : b0;
    int mBase = blockIdx.x * 128;
    int nBase = blockIdx.y * 128;

    __shared__ __align__(16) unsigned short As[128 * 64];
    __shared__ __align__(16) unsigned short Bs[128 * 64];

    int tid = threadIdx.x;
    int lane = tid & 63, wid = tid >> 6;
    int warpM = wid >> 1, warpN = wid & 1;

    f32x4 acc[4][4];
    #pragma unroll
    for (int i = 0; i < 4; ++i)
        #pragma unroll
        for (int j = 0; j < 4; ++j) acc[i][j] = (f32x4){0.f, 0.f, 0.f, 0.f};

    for (int kt = 0; kt < 4; ++kt) {
        int k0 = kt * 64;
        __syncthreads();
        #pragma unroll
        for (int i = 0; i < 4; ++i) {
            int c = tid + i * 256;
            int row = c >> 3, cc = c & 7;
            int gr = mBase + row; if (gr > NN - 1) gr = NN - 1;
            u32x4 av = *(const u32x4*)(A + (size_t)gr * CC + k0 + cc * 8);
            int sb = row * 128 + ((cc * 16) ^ ((row & 7) << 4));
            *(u32x4*)((char*)As + sb) = av;
            u32x4 bv = *(const u32x4*)(W + (nBase + row) * 256 + k0 + cc * 8);
            *(u32x4*)((char*)Bs + sb) = bv;
        }
        __syncthreads();
        #pragma unroll
        for (int kk = 0; kk < 2; ++kk) {
            bf16x8 af[4], bfr[4];
            int kb = kk * 64 + (lane >> 4) * 16;
            #pragma unroll
            for (int mi = 0; mi < 4; ++mi) {
                int row = warpM * 64 + mi * 16 + (lane & 15);
                int sb = row * 128 + (kb ^ ((row & 7) << 4));
                af[mi] = *(const bf16x8*)((const char*)As + sb);
            }
            #pragma unroll
            for (int ni = 0; ni < 4; ++ni) {
                int row = warpN * 64 + ni * 16 + (lane & 15);
                int sb = row * 128 + (kb ^ ((row & 7) << 4));
                bfr[ni] = *(const bf16x8*)((const char*)Bs + sb);
            }
            #pragma unroll
            for (int mi = 0; mi < 4; ++mi)
                #pragma unroll
                for (int ni = 0; ni < 4; ++ni)
                    acc[mi][ni] = __builtin_amdgcn_mfma_f32_16x16x32_bf16(af[mi], bfr[ni], acc[mi][ni], 0, 0, 0);
        }
    }

    float alpha = 1.f / (1.f + __expf(-skip[z]));
    const float* hres = z ? hB : hA;

    #pragma unroll
    for (int mi = 0; mi < 4; ++mi) {
        #pragma unroll
        for (int ni = 0; ni < 4; ++ni) {
            int col = nBase + warpN * 64 + ni * 16 + (lane & 15);
            int row0 = mBase + warpM * 64 + mi * 16 + (lane >> 4) * 4;
            float b = bias[col];
            #pragma unroll
            for (int j = 0; j < 4; ++j) {
                int row = row0 + j;
                if (row < NN) {
                    float val = acc[mi][ni][j] + b;
                    float hv = hres[(size_t)row * CC + col];
                    OutF[(size_t)z * NS + (size_t)row * CC + col] = val * alpha + hv * (1.f - alpha);
                }
            }
        }
    }
}

// ---------------------------------------------------------------------------
// Edge aggregation, ALL relations in one launch (round-13 fused structure).
// Wave w < NN: type-B dst (r0 + r2 in-register, averaged) -> TbB.
// Wave w in [NN,2NN): type-A dst (r1) -> TbA.
// fp8 K/V (512B/src row), packed pk decode, exp2 softmax, 1-edge prefetch.
// ---------------------------------------------------------------------------
__device__ __forceinline__ void agg_pass(const unsigned char* __restrict__ KV,
                                         const int* __restrict__ srcS,
                                         int beg, int end, int lane,
                                         float q0, float q1, float q2, float q3, float ps2,
                                         float& o0, float& o1, float& o2, float& o3)
{
    float l = 0.f;
    float a0 = 0.f, a1 = 0.f, a2 = 0.f, a3 = 0.f;
    int n = end - beg;
    if (n > 0) {
        int p0 = beg + lane;
        int idx = srcS[p0 < end ? p0 : end - 1];
        int s = __shfl(idx, 0);
        unsigned int kw = *(const unsigned int*)(KV + (size_t)s * 512 + lane * 4);
        unsigned int vw = *(const unsigned int*)(KV + (size_t)s * 512 + 256 + lane * 4);
        for (int j = 0; j < n; ++j) {
            unsigned int kc = kw, vc = vw;
            int jn = j + 1;
            if (jn < n) {
                if ((jn & 63) == 0) {
                    int p = beg + jn + lane;
                    idx = srcS[p < end ? p : end - 1];
                }
                int sn = __shfl(idx, jn & 63);
                kw = *(const unsigned int*)(KV + (size_t)sn * 512 + lane * 4);
                vw = *(const unsigned int*)(KV + (size_t)sn * 512 + 256 + lane * 4);
            }
            f32x2 k01 = fp8pair<false>(kc), k23 = fp8pair<true>(kc);
            float d = fmaf(q0, k01[0], fmaf(q1, k01[1], fmaf(q2, k23[0], q3 * k23[1])));
            d += __shfl_xor(d, 1);
            d += __shfl_xor(d, 2);
            d += __shfl_xor(d, 4);
            float pw = exp2f(d * ps2);
            l += pw;
            f32x2 v01 = fp8pair<false>(vc), v23 = fp8pair<true>(vc);
            a0 = fmaf(pw, v01[0], a0);
            a1 = fmaf(pw, v01[1], a1);
            a2 = fmaf(pw, v23[0], a2);
            a3 = fmaf(pw, v23[1], a3);
        }
    }
    float inv = (l > 0.f) ? 1.f / l : 0.f;
    o0 = a0 * inv; o1 = a1 * inv; o2 = a2 * inv; o3 = a3 * inv;
}

__global__ __launch_bounds__(256)
void agg_all_kernel(const unsigned short* __restrict__ Q0, const unsigned short* __restrict__ Q1,
                    const unsigned char* __restrict__ KV0, const unsigned char* __restrict__ KV1,
                    const unsigned char* __restrict__ KV2,
                    const int* __restrict__ offs, const int* __restrict__ srcS,
                    const float* __restrict__ rel_pri,
                    unsigned short* __restrict__ TbA, unsigned short* __restrict__ TbB)
{
    int w = (blockIdx.x * 256 + threadIdx.x) >> 6;
    int lane = threadIdx.x & 63;
    int h = lane >> 3;
    const float rs2 = 0.17677669529663687f * 1.4426950408889634f;  // /sqrt(32)*log2(e)

    if (w < NN) {
        int d = w;
        u32x2 qv = *(const u32x2*)(Q1 + (size_t)d * CC + lane * 4);
        float q0 = bf2f(qv[0] & 0xffffu), q1 = bf2f(qv[0] >> 16);
        float q2 = bf2f(qv[1] & 0xffffu), q3 = bf2f(qv[1] >> 16);
        float x0, x1, x2, x3, y0, y1, y2, y3;
        agg_pass(KV0, (const int*)srcS, offs[d], offs[d + 1], lane,
                 q0, q1, q2, q3, rel_pri[h] * rs2, x0, x1, x2, x3);
        const int* off2 = offs + 2 * (NN + 1);
        agg_pass(KV2, (const int*)srcS + 2 * EE, off2[d], off2[d + 1], lane,
                 q0, q1, q2, q3, rel_pri[16 + h] * rs2, y0, y1, y2, y3);
        unsigned short* out = TbB + (size_t)d * CC + lane * 4;
        u32x2 o;
        o[0] = (unsigned)f2bf((x0 + y0) * 0.5f) | ((unsigned)f2bf((x1 + y1) * 0.5f) << 16);
        o[1] = (unsigned)f2bf((x2 + y2) * 0.5f) | ((unsigned)f2bf((x3 + y3) * 0.5f) << 16);
        *(u32x2*)out = o;
    } else if (w < 2 * NN) {
        int d = w - NN;
        u32x2 qv = *(const u32x2*)(Q0 + (size_t)d * CC + lane * 4);
        float q0 = bf2f(qv[0] & 0xffffu), q1 = bf2f(qv[0] >> 16);
        float q2 = bf2f(qv[1] & 0xffffu), q3 = bf2f(qv[1] >> 16);
        float x0, x1, x2, x3;
        const int* off1 = offs + (NN + 1);
        agg_pass(KV1, (const int*)srcS + EE, off1[d], off1[d + 1], lane,
                 q0, q1, q2, q3, rel_pri[8 + h] * rs2, x0, x1, x2, x3);
        unsigned short* out = TbA + (size_t)d * CC + lane * 4;
        u32x2 o;
        o[0] = (unsigned)f2bf(x0) | ((unsigned)f2bf(x1) << 16);
        o[1] = (unsigned)f2bf(x2) | ((unsigned)f2bf(x3) << 16);
        *(u32x2*)out = o;
    }
}

// ---------------------------------------------------------------------------
extern "C" void kernel_launch(void* const* d_in, const int* in_sizes, int n_in,
                              void* d_out, int out_size, void* d_ws, size_t ws_size,
                              hipStream_t stream)
{
    const float* hA = (const float*)d_in[0];
    const float* hB = (const float*)d_in[1];
    const int* src0 = (const int*)d_in[2];
    const int* dst0 = (const int*)d_in[3];
    const int* src1 = (const int*)d_in[4];
    const int* dst1 = (const int*)d_in[5];
    const int* src2 = (const int*)d_in[6];
    const int* dst2 = (const int*)d_in[7];
    const float* Wk = (const float*)d_in[8];
    const float* bk = (const float*)d_in[9];
    const float* Wq = (const float*)d_in[10];
    const float* bq = (const float*)d_in[11];
    const float* Wv = (const float*)d_in[12];
    const float* bv = (const float*)d_in[13];
    const float* Wa = (const float*)d_in[14];
    const float* ba = (const float*)d_in[15];
    const float* rel_att = (const float*)d_in[16];
    const float* rel_msg = (const float*)d_in[17];
    const float* rel_pri = (const float*)d_in[18];
    const float* skip = (const float*)d_in[19];

    char* w = (char*)d_ws;
    auto alloc = [&](size_t bytes) {
        char* p = w;
        w += (bytes + 255) & ~(size_t)255;
        return p;
    };
    // ws total ~140 MB
    unsigned short* WT  = (unsigned short*)alloc((size_t)10 * 65536 * 2);
    float* ball         = (float*)alloc((size_t)8 * 256 * 4);
    unsigned short* Qb  = (unsigned short*)alloc((size_t)2 * NS * 2);   // Q0,Q1 (bf16)
    unsigned char* KV0  = (unsigned char*)alloc((size_t)NN * 512);      // r0 K|V fp8
    unsigned short* Tb  = (unsigned short*)alloc((size_t)2 * NS * 2);   // tA, tB (bf16)
    int* offs           = (int*)alloc((size_t)3 * (NN + 1) * 4);
    int* srcS           = (int*)alloc((size_t)3 * EE * 4);
    int* bcnt           = (int*)alloc((size_t)3 * NBK * 4);
    int* bbase          = (int*)alloc((size_t)3 * (NBK + 1) * 4);
    int* bcur           = (int*)alloc((size_t)3 * NBK * 4);

    // d_out (102.4 MB, dead until out_gemm): KV1 | KV2 | h_bf (bf16 hA,hB)
    unsigned char* dob = (unsigned char*)d_out;
    unsigned char* KV1 = dob;
    unsigned char* KV2 = dob + (size_t)NN * 512;
    unsigned short* h_bf = (unsigned short*)(dob + (size_t)2 * NN * 512);

    (void)hipMemsetAsync(bcnt, 0, (size_t)3 * NBK * 4, stream);

    // tobf + prep weights + P0 bucket histogram (fused, disjoint block ranges)
    setup_kernel<<<TOBF_BLKS + PREP_BLKS + 3 * NT1, 256, 0, stream>>>(
        hA, hB, h_bf, Wk, bk, Wq, bq, Wv, bv, Wa,
        rel_att, rel_msg, WT, ball, dst0, dst1, dst2, bcnt);
    bscan_kernel<<<3, 1024, 0, stream>>>(bcnt, bbase, bcur);
    p1_kernel<<<3 * NT1, 256, 0, stream>>>(src0, src1, src2, dst0, dst1, dst2,
                                           bcur, (unsigned int*)srcS);
    p2_kernel<<<3 * NBK, 256, 0, stream>>>(bbase, (unsigned int*)srcS, offs);

    // all 8 production GEMMs; (slot,ntile) fastest -> A-tile L3 reuse
    gemm8_kernel<<<391 * 16, 256, 0, stream>>>(h_bf, WT, ball, Qb, KV0, KV1, KV2);

    // all 3 relations' aggregation in one launch (r0+r2 fused per B-wave)
    agg_all_kernel<<<25000, 256, 0, stream>>>(Qb, Qb + NS, KV0, KV1, KV2,
                                              offs, srcS, rel_pri, Tb, Tb + NS);

    // output GEMM overwrites d_out (reads Tb/WT/ba/hA/hB/skip only)
    out_gemm_kernel<<<dim3(391, 2, 2), 256, 0, stream>>>(
        Tb, Tb + NS, WT + 8 * 65536, WT + 9 * 65536, ba, ba + 256,
        (float*)d_out, hA, hB, skip);
}